// Round 8
// baseline (155.651 us; speedup 1.0000x reference)
//
#include <hip/hip_runtime.h>
#include <math.h>

#define N_NODES 10000
#define N_EDGES 320000
#define IN_DIM  128
#define HID     256
#define CAP     128      // bucket capacity; Poisson(32) => overflow prob ~0
#define NWB     64       // W-path blocks
#define NXB     128      // x->bf16 convert blocks
#define NFB     448      // fill blocks
#define NBB     (NXB + NFB)   // K_B grid: 576

typedef __attribute__((ext_vector_type(8))) short frag_ab;
typedef __attribute__((ext_vector_type(4))) float frag_cd;

// ---------------- workspace layout (bytes) ----------------
// cursor @ 0         : 40,000    (in-degree counters, atomicAdd; memset to 0)
// wct    @ 40,064    : 65,536    (WcT packed bf16x2 [n=256][64])
// bc     @ 105,600   : 1,024     (bp @ Wev)
// xb     @ 106,624   : 2,560,000 (x packed bf16x2, L2-resident gather source)
// yb     @ 2,666,624 : 2,560,000 (aggregated y, packed bf16x2)
// rs     @ 5,226,624 : 40,000    (dinv * wsum per node)
// bucket @ 5,266,624 : 5,120,000 (edge buckets)

__device__ __forceinline__ unsigned bf16rne(float f) {
    union { float f; unsigned u; } c; c.f = f;
    return (c.u + 0x7FFFu + ((c.u >> 16) & 1u)) >> 16;
}
__device__ __forceinline__ float sig_f(float x)  { return 1.f / (1.f + __expf(-x)); }
__device__ __forceinline__ float tanh_f(float x) { return 1.f - 2.f / (1.f + __expf(2.f * x)); }

// ===== K_W: block-local gates->LSTM->Wc (64 blocks; 1 block/CU -> LDS never binds) =====
__global__ __launch_bounds__(256, 2)
void k_w(const float* __restrict__ Wp, const float* __restrict__ bp,
         const float* __restrict__ wih, const float* __restrict__ whh,
         const float* __restrict__ b_ih, const float* __restrict__ b_hh,
         const float* __restrict__ iw,
         unsigned* __restrict__ wct, float* __restrict__ bc) {
    __shared__ __align__(16) char smem_raw[57920];
    const int bid = blockIdx.x;
    const int t = threadIdx.x;

    // Block b owns gate columns: n_local = q*4+jj <-> global n = q*256 + 4b + jj.
    float (*aT)[260]  = (float(*)[260])smem_raw;               // [32k][256m] iw^T tile
    float (*bSt)[20]  = (float(*)[20])(smem_raw + 33280);      // [256k][16n] Wih+Whh
    float (*iwc)[260] = (float(*)[260])(smem_raw + 53760);     // [4jj][256r] iw columns
    #pragma unroll
    for (int n = 0; n < 16; ++n) {
        int nrow = (n >> 2) * 256 + 4 * bid + (n & 3);
        bSt[t][n] = wih[nrow * 256 + t] + whh[nrow * 256 + t];
    }
    const int mg = t >> 2, ng = t & 3;
    const int srow = t >> 3, sf4 = t & 7;      // coalesced staging map (128B segments)
    float acc[4][4] = {};
    for (int kt = 0; kt < 8; ++kt) {
        int k0 = kt * 32;
        __syncthreads();
        #pragma unroll
        for (int rr = 0; rr < 8; ++rr) {
            int row = srow + 32 * rr;
            float4 v = *(const float4*)&iw[row * 256 + k0 + 4 * sf4];
            aT[4 * sf4 + 0][row] = v.x; aT[4 * sf4 + 1][row] = v.y;
            aT[4 * sf4 + 2][row] = v.z; aT[4 * sf4 + 3][row] = v.w;
        }
        __syncthreads();
        if (kt == (bid >> 3)) {                // iw cols 4b..4b+3 live in this tile
            int c0 = (4 * bid) & 31;
            #pragma unroll
            for (int jj = 0; jj < 4; ++jj) iwc[jj][t] = aT[c0 + jj][t];
        }
        #pragma unroll 4
        for (int kk = 0; kk < 32; ++kk) {
            float4 a4 = *(const float4*)&aT[kk][4 * mg];
            float4 b4 = *(const float4*)&bSt[k0 + kk][4 * ng];
            float a[4] = {a4.x, a4.y, a4.z, a4.w};
            float b[4] = {b4.x, b4.y, b4.z, b4.w};
            #pragma unroll
            for (int i = 0; i < 4; ++i)
                #pragma unroll
                for (int j = 0; j < 4; ++j)
                    acc[i][j] = fmaf(a[i], b[j], acc[i][j]);
        }
    }
    float (*gates_lds)[17] = (float(*)[17])smem_raw;           // [256][17]
    float (*wevc)[260]     = (float(*)[260])(smem_raw + 33280);// [4jj][256k]
    __syncthreads();
    #pragma unroll
    for (int i = 0; i < 4; ++i)
        #pragma unroll
        for (int j = 0; j < 4; ++j)
            gates_lds[4 * mg + i][4 * ng + j] = acc[i][j];
    __syncthreads();
    {
        int r = t;
        #pragma unroll
        for (int jj = 0; jj < 4; ++jj) {
            int jcol = 4 * bid + jj;
            float gi = gates_lds[r][0  + jj] + b_ih[jcol]       + b_hh[jcol];
            float gf = gates_lds[r][4  + jj] + b_ih[256 + jcol] + b_hh[256 + jcol];
            float gg = gates_lds[r][8  + jj] + b_ih[512 + jcol] + b_hh[512 + jcol];
            float go = gates_lds[r][12 + jj] + b_ih[768 + jcol] + b_hh[768 + jcol];
            float c  = sig_f(gf) * iwc[jj][r] + sig_f(gi) * tanh_f(gg);
            wevc[jj][r] = sig_f(go) * tanh_f(c);
        }
    }
    float (*wpT)[132] = (float(*)[132])smem_raw;               // [32kk][128a+pad]
    const int a2 = t & 63, jj = t >> 6;
    float c0 = 0.f, c1 = 0.f;
    for (int kt2 = 0; kt2 < 8; ++kt2) {
        int k0 = kt2 * 32;
        __syncthreads();                       // wpT reuse guard (also closes LSTM)
        #pragma unroll
        for (int ri = 0; ri < 4; ++ri) {
            int a = srow + 32 * ri;            // 0..127
            float4 v = *(const float4*)&Wp[a * 256 + k0 + 4 * sf4];
            wpT[4 * sf4 + 0][a] = v.x; wpT[4 * sf4 + 1][a] = v.y;
            wpT[4 * sf4 + 2][a] = v.z; wpT[4 * sf4 + 3][a] = v.w;
        }
        __syncthreads();
        #pragma unroll 8
        for (int kk = 0; kk < 32; ++kk) {
            float2 wv = *(const float2*)&wpT[kk][2 * a2];
            float wev = wevc[jj][k0 + kk];     // wave-uniform broadcast
            c0 = fmaf(wv.x, wev, c0);
            c1 = fmaf(wv.y, wev, c1);
        }
    }
    wct[(4 * bid + jj) * 64 + a2] = bf16rne(c0) | (bf16rne(c1) << 16);
    if (t < 4) {   // bias column: bc[4b+t] = bp . wevc[t]
        float s = 0.f;
        #pragma unroll 4
        for (int k4 = 0; k4 < 64; ++k4) {
            float4 b4 = *(const float4*)&bp[4 * k4];
            float4 w4 = *(const float4*)&wevc[t][4 * k4];
            s = fmaf(b4.x, w4.x, fmaf(b4.y, w4.y, fmaf(b4.z, w4.z, fmaf(b4.w, w4.w, s))));
        }
        bc[4 * bid + t] = s;
    }
}

// ===== K_B: x->bf16 (blocks 0..127) | bucket fill (128..575) — ZERO LDS, full TLP =====
__global__ __launch_bounds__(256)
void k_b(const float* __restrict__ x, const int* __restrict__ ei,
         int* __restrict__ cursor, unsigned* __restrict__ xb,
         int* __restrict__ bucket) {
    const int bid = blockIdx.x;
    const int t = threadIdx.x;
    if (bid < NXB) {
        const float4* x4 = (const float4*)x;
        uint2* xb2 = (uint2*)xb;
        for (int idx = bid * 256 + t; idx < N_NODES * 32; idx += NXB * 256) {
            float4 v = x4[idx];
            xb2[idx] = make_uint2(bf16rne(v.x) | (bf16rne(v.y) << 16),
                                  bf16rne(v.z) | (bf16rne(v.w) << 16));
        }
    } else {
        for (int u = (bid - NXB) * 256 + t; u < N_EDGES / 4; u += NFB * 256) {
            int4 s4 = *(const int4*)&ei[u * 4];
            int4 d4 = *(const int4*)&ei[N_EDGES + u * 4];
            int p0 = atomicAdd(&cursor[d4.x], 1);
            if (p0 < CAP) bucket[d4.x * CAP + p0] = s4.x;
            int p1 = atomicAdd(&cursor[d4.y], 1);
            if (p1 < CAP) bucket[d4.y * CAP + p1] = s4.y;
            int p2 = atomicAdd(&cursor[d4.z], 1);
            if (p2 < CAP) bucket[d4.z * CAP + p2] = s4.z;
            int p3 = atomicAdd(&cursor[d4.w], 1);
            if (p3 < CAP) bucket[d4.w * CAP + p3] = s4.w;
        }
    }
}

// ===== K_agg: 2500 blocks, 1 node/wave, zero LDS -> 10000 waves of TLP =====
__global__ __launch_bounds__(256)
void k_agg(const unsigned* __restrict__ xb, const int* __restrict__ cursor,
           const int* __restrict__ bucket, unsigned* __restrict__ yb,
           float* __restrict__ rs) {
    const int t = threadIdx.x;
    const int wv = t >> 6, lane = t & 63;
    const int v = blockIdx.x * 4 + wv;     // < 10000
    int cntv = cursor[v];
    float dv = rsqrtf((float)(cntv + 1));
    int cnt2 = cntv > CAP ? CAP : cntv;
    unsigned self = xb[v * 64 + lane];
    union { unsigned u; float f; } c0, c1;
    c0.u = self << 16; c1.u = self & 0xFFFF0000u;
    float acc0 = dv * c0.f, acc1 = dv * c1.f, wsum = dv;
    const int4* bkt4 = (const int4*)&bucket[v * CAP];
    int j = 0;
    for (; j + 8 <= cnt2; j += 8) {
        int4 sa = bkt4[j >> 2];
        int4 sb = bkt4[(j >> 2) + 1];
        float w0 = rsqrtf((float)(cursor[sa.x] + 1));
        float w1 = rsqrtf((float)(cursor[sa.y] + 1));
        float w2 = rsqrtf((float)(cursor[sa.z] + 1));
        float w3 = rsqrtf((float)(cursor[sa.w] + 1));
        float w4 = rsqrtf((float)(cursor[sb.x] + 1));
        float w5 = rsqrtf((float)(cursor[sb.y] + 1));
        float w6 = rsqrtf((float)(cursor[sb.z] + 1));
        float w7 = rsqrtf((float)(cursor[sb.w] + 1));
        unsigned r0 = xb[sa.x * 64 + lane];
        unsigned r1 = xb[sa.y * 64 + lane];
        unsigned r2 = xb[sa.z * 64 + lane];
        unsigned r3 = xb[sa.w * 64 + lane];
        unsigned r4 = xb[sb.x * 64 + lane];
        unsigned r5 = xb[sb.y * 64 + lane];
        unsigned r6 = xb[sb.z * 64 + lane];
        unsigned r7 = xb[sb.w * 64 + lane];
        union { unsigned u; float f; } a0, a1;
        a0.u = r0 << 16; a1.u = r0 & 0xFFFF0000u;
        acc0 = fmaf(w0, a0.f, acc0); acc1 = fmaf(w0, a1.f, acc1);
        a0.u = r1 << 16; a1.u = r1 & 0xFFFF0000u;
        acc0 = fmaf(w1, a0.f, acc0); acc1 = fmaf(w1, a1.f, acc1);
        a0.u = r2 << 16; a1.u = r2 & 0xFFFF0000u;
        acc0 = fmaf(w2, a0.f, acc0); acc1 = fmaf(w2, a1.f, acc1);
        a0.u = r3 << 16; a1.u = r3 & 0xFFFF0000u;
        acc0 = fmaf(w3, a0.f, acc0); acc1 = fmaf(w3, a1.f, acc1);
        a0.u = r4 << 16; a1.u = r4 & 0xFFFF0000u;
        acc0 = fmaf(w4, a0.f, acc0); acc1 = fmaf(w4, a1.f, acc1);
        a0.u = r5 << 16; a1.u = r5 & 0xFFFF0000u;
        acc0 = fmaf(w5, a0.f, acc0); acc1 = fmaf(w5, a1.f, acc1);
        a0.u = r6 << 16; a1.u = r6 & 0xFFFF0000u;
        acc0 = fmaf(w6, a0.f, acc0); acc1 = fmaf(w6, a1.f, acc1);
        a0.u = r7 << 16; a1.u = r7 & 0xFFFF0000u;
        acc0 = fmaf(w7, a0.f, acc0); acc1 = fmaf(w7, a1.f, acc1);
        wsum += w0 + w1 + w2 + w3 + w4 + w5 + w6 + w7;
    }
    for (; j < cnt2; ++j) {
        int s = bucket[v * CAP + j];
        float ws = rsqrtf((float)(cursor[s] + 1));
        unsigned rr = xb[s * 64 + lane];
        union { unsigned u; float f; } a0, a1;
        a0.u = rr << 16; a1.u = rr & 0xFFFF0000u;
        acc0 = fmaf(ws, a0.f, acc0); acc1 = fmaf(ws, a1.f, acc1);
        wsum += ws;
    }
    yb[v * 64 + lane] = bf16rne(dv * acc0) | (bf16rne(dv * acc1) << 16);
    if (lane == 0) rs[v] = dv * wsum;
}

// ===== K_out: out[10000,256] = yb @ WcT^T + rs*bc + b_gcn (bf16 MFMA; r0-verified) =====
__global__ __launch_bounds__(256)
void k_out(const unsigned* __restrict__ yb, const unsigned* __restrict__ wct,
           const float* __restrict__ bc, const float* __restrict__ rs,
           const float* __restrict__ b_gcn, float* __restrict__ out) {
    int m0 = blockIdx.x * 16;
    int w = threadIdx.x >> 6, lane = threadIdx.x & 63;
    int q = lane >> 4, ln = lane & 15;
    const int4* yb4  = (const int4*)yb;   // row stride 16 int4
    const int4* wct4 = (const int4*)wct;
    union { int4 v; frag_ab f; } a[4];
    #pragma unroll
    for (int kc = 0; kc < 4; ++kc)
        a[kc].v = yb4[(m0 + ln) * 16 + kc * 4 + q];
    float rsv[4];
    #pragma unroll
    for (int r = 0; r < 4; ++r) rsv[r] = rs[m0 + q * 4 + r];
    #pragma unroll
    for (int i = 0; i < 4; ++i) {
        int n0 = (w + 4 * i) * 16;
        union { int4 v; frag_ab f; } b[4];
        #pragma unroll
        for (int kc = 0; kc < 4; ++kc)
            b[kc].v = wct4[(n0 + ln) * 16 + kc * 4 + q];
        frag_cd acc = {0.f, 0.f, 0.f, 0.f};
        #pragma unroll
        for (int kc = 0; kc < 4; ++kc)
            acc = __builtin_amdgcn_mfma_f32_16x16x32_bf16(a[kc].f, b[kc].f, acc, 0, 0, 0);
        int n = n0 + ln;
        float bcv = bc[n], bgv = b_gcn[n];
        #pragma unroll
        for (int r = 0; r < 4; ++r) {
            int m = m0 + q * 4 + r;
            out[m * HID + n] = acc[r] + rsv[r] * bcv + bgv;
        }
    }
}

extern "C" void kernel_launch(void* const* d_in, const int* in_sizes, int n_in,
                              void* d_out, int out_size, void* d_ws, size_t ws_size,
                              hipStream_t stream) {
    const float* x     = (const float*)d_in[0];
    const int*   ei    = (const int*)d_in[1];
    const float* Wp    = (const float*)d_in[2];
    const float* bp    = (const float*)d_in[3];
    const float* W_ih  = (const float*)d_in[4];
    const float* W_hh  = (const float*)d_in[5];
    const float* b_ih  = (const float*)d_in[6];
    const float* b_hh  = (const float*)d_in[7];
    const float* iw    = (const float*)d_in[8];
    const float* b_gcn = (const float*)d_in[9];
    float* out = (float*)d_out;

    char* ws = (char*)d_ws;
    int*      cursor = (int*)     (ws + 0);
    unsigned* wct    = (unsigned*)(ws + 40064);
    float*    bc     = (float*)   (ws + 105600);
    unsigned* xb     = (unsigned*)(ws + 106624);
    unsigned* yb     = (unsigned*)(ws + 2666624);
    float*    rs     = (float*)   (ws + 5226624);
    int*      bucket = (int*)     (ws + 5266624);

    hipMemsetAsync(cursor, 0, N_NODES * sizeof(int), stream);

    k_w  <<<NWB, 256, 0, stream>>>(Wp, bp, W_ih, W_hh, b_ih, b_hh, iw, wct, bc);
    k_b  <<<NBB, 256, 0, stream>>>(x, ei, cursor, xb, bucket);
    k_agg<<<2500, 256, 0, stream>>>(xb, cursor, bucket, yb, rs);
    k_out<<<625, 256, 0, stream>>>(yb, wct, bc, rs, b_gcn, out);
}

// Round 9
// 148.682 us; speedup vs baseline: 1.0469x; 1.0469x over previous
//
#include <hip/hip_runtime.h>
#include <math.h>

#define N_NODES 10000
#define N_EDGES 320000
#define IN_DIM  128
#define HID     256
#define CAP     128      // bucket capacity; Poisson(32) => overflow prob ~0
#define NWB     64       // W-path blocks inside k_wagg
#define NXB     128      // x->bf16 convert blocks
#define NFB     448      // fill blocks
#define NBB     (NXB + NFB)

typedef __attribute__((ext_vector_type(8))) short frag_ab;
typedef __attribute__((ext_vector_type(4))) float frag_cd;

// ---------------- workspace layout (bytes) ----------------
// cursor @ 0         : 40,000    (in-degree counters, atomicAdd; memset to 0)
// wct    @ 40,064    : 65,536    (WcT packed bf16x2 [n=256][64])
// bc     @ 105,600   : 1,024     (bp @ Wev)
// xb     @ 106,624   : 2,560,000 (x packed bf16x2, L2-resident gather source)
// yb     @ 2,666,624 : 2,560,000 (aggregated y, packed bf16x2)
// rs     @ 5,226,624 : 40,000    (dinv * wsum per node)
// bucket @ 5,266,624 : 5,120,000 (edge buckets)

__device__ __forceinline__ unsigned bf16rne(float f) {
    union { float f; unsigned u; } c; c.f = f;
    return (c.u + 0x7FFFu + ((c.u >> 16) & 1u)) >> 16;
}
__device__ __forceinline__ float sig_f(float x)  { return 1.f / (1.f + __expf(-x)); }
__device__ __forceinline__ float tanh_f(float x) { return 1.f - 2.f / (1.f + __expf(2.f * x)); }

// ===== K1 (k_fx): x->bf16 (blocks 0..127) | bucket fill (128..575) — zero LDS =====
__global__ __launch_bounds__(256)
void k_fx(const float* __restrict__ x, const int* __restrict__ ei,
          int* __restrict__ cursor, unsigned* __restrict__ xb,
          int* __restrict__ bucket) {
    const int bid = blockIdx.x;
    const int t = threadIdx.x;
    if (bid < NXB) {
        const float4* x4 = (const float4*)x;
        uint2* xb2 = (uint2*)xb;
        for (int idx = bid * 256 + t; idx < N_NODES * 32; idx += NXB * 256) {
            float4 v = x4[idx];
            xb2[idx] = make_uint2(bf16rne(v.x) | (bf16rne(v.y) << 16),
                                  bf16rne(v.z) | (bf16rne(v.w) << 16));
        }
    } else {
        for (int u = (bid - NXB) * 256 + t; u < N_EDGES / 4; u += NFB * 256) {
            int4 s4 = *(const int4*)&ei[u * 4];
            int4 d4 = *(const int4*)&ei[N_EDGES + u * 4];
            int p0 = atomicAdd(&cursor[d4.x], 1);
            if (p0 < CAP) bucket[d4.x * CAP + p0] = s4.x;
            int p1 = atomicAdd(&cursor[d4.y], 1);
            if (p1 < CAP) bucket[d4.y * CAP + p1] = s4.y;
            int p2 = atomicAdd(&cursor[d4.z], 1);
            if (p2 < CAP) bucket[d4.z * CAP + p2] = s4.z;
            int p3 = atomicAdd(&cursor[d4.w], 1);
            if (p3 < CAP) bucket[d4.w * CAP + p3] = s4.w;
        }
    }
}

// ===== K2 (k_wagg): W-path (blocks 0..63, 21.3KB LDS) + aggregation (64..2563) =====
// W latency (1 block/CU alone would be 1 wave/SIMD) hides under co-resident agg waves.
__global__ __launch_bounds__(256, 5)
void k_wagg(const float* __restrict__ Wp, const float* __restrict__ bp,
            const float* __restrict__ wih, const float* __restrict__ whh,
            const float* __restrict__ b_ih, const float* __restrict__ b_hh,
            const float* __restrict__ iw,
            const unsigned* __restrict__ xb, const int* __restrict__ cursor,
            const int* __restrict__ bucket,
            unsigned* __restrict__ wct, float* __restrict__ bc,
            unsigned* __restrict__ yb, float* __restrict__ rs) {
    __shared__ __align__(16) char smem_raw[21760];   // 21.25 KB -> 7 blocks/CU (LDS)
    const int bid = blockIdx.x;
    const int t = threadIdx.x;

    if (bid < NWB) {
        // Block b owns gate columns jcol = 4b+jj; gate q at n_global = q*256 + jcol.
        const int b = bid;
        float (*aT)[256]   = (float(*)[256])smem_raw;             // [16kk][256m] iw^T tile (16KB)
        float (*bS)[20]    = (float(*)[20])(smem_raw + 16384);    // [16kk][16n] Wih+Whh (1.28KB)
        float (*wevc)[256] = (float(*)[256])(smem_raw + 17664);   // [4jj][256k] Wev cols (4KB)
        float gacc[16] = {};                                      // gates[m=t][q*4+jj]
        float riw[4];                                             // iw[t][4b+jj]
        const int c0 = (4 * b) & 15, ktiw = (4 * b) >> 4;
        for (int kt = 0; kt < 16; ++kt) {
            int k0 = kt * 16;
            __syncthreads();                                      // aT/bS reuse guard
            #pragma unroll
            for (int rr = 0; rr < 4; ++rr) {                      // stage aT[kk][m]=iw[m][k0+kk]
                int row = (t >> 2) + 64 * rr;
                int kq = t & 3;
                float4 v = *(const float4*)&iw[row * 256 + k0 + 4 * kq];
                aT[4 * kq + 0][row] = v.x; aT[4 * kq + 1][row] = v.y;
                aT[4 * kq + 2][row] = v.z; aT[4 * kq + 3][row] = v.w;
            }
            {                                                     // stage bS[kk][n]
                int n = t >> 4, kk = t & 15;
                int nrow = (n >> 2) * 256 + 4 * b + (n & 3);
                bS[kk][n] = wih[nrow * 256 + k0 + kk] + whh[nrow * 256 + k0 + kk];
            }
            __syncthreads();
            if (kt == ktiw) {                                     // iw cols 4b..4b+3 in this tile
                #pragma unroll
                for (int jj = 0; jj < 4; ++jj) riw[jj] = aT[c0 + jj][t];
            }
            #pragma unroll
            for (int kk = 0; kk < 16; ++kk) {                     // rank-16 outer product
                float a = aT[kk][t];
                #pragma unroll
                for (int n = 0; n < 16; ++n)
                    gacc[n] = fmaf(a, bS[kk][n], gacc[n]);
            }
        }
        // LSTM nonlinearity (all register-local; biases are broadcast loads)
        #pragma unroll
        for (int jj = 0; jj < 4; ++jj) {
            int jcol = 4 * b + jj;
            float gi = gacc[0 + jj]  + b_ih[jcol]       + b_hh[jcol];
            float gf = gacc[4 + jj]  + b_ih[256 + jcol] + b_hh[256 + jcol];
            float gg = gacc[8 + jj]  + b_ih[512 + jcol] + b_hh[512 + jcol];
            float go = gacc[12 + jj] + b_ih[768 + jcol] + b_hh[768 + jcol];
            float c  = sig_f(gf) * riw[jj] + sig_f(gi) * tanh_f(gg);
            wevc[jj][t] = sig_f(go) * tanh_f(c);
        }
        // Wc: wct[(4b+jj)*64+a2] = bf16x2(Wp[2a2].wev[jj], Wp[2a2+1].wev[jj])
        float (*wpT)[128] = (float(*)[128])smem_raw;              // [16kk][128a] reuse aT (8KB)
        const int a2 = t & 63, jj = t >> 6;
        float cc0 = 0.f, cc1 = 0.f;
        for (int kt = 0; kt < 16; ++kt) {
            int k0 = kt * 16;
            __syncthreads();                  // closes wevc writes (kt=0) / wpT reuse
            #pragma unroll
            for (int h = 0; h < 2; ++h) {     // stage wpT[kk][a]=Wp[a][k0+kk]
                int item = t + 256 * h;
                int a = item >> 2, ch = item & 3;
                float4 v = *(const float4*)&Wp[a * 256 + k0 + 4 * ch];
                wpT[4 * ch + 0][a] = v.x; wpT[4 * ch + 1][a] = v.y;
                wpT[4 * ch + 2][a] = v.z; wpT[4 * ch + 3][a] = v.w;
            }
            __syncthreads();
            #pragma unroll
            for (int kk = 0; kk < 16; ++kk) {
                float2 wv = *(const float2*)&wpT[kk][2 * a2];
                float wev = wevc[jj][k0 + kk];                    // wave-uniform broadcast
                cc0 = fmaf(wv.x, wev, cc0);
                cc1 = fmaf(wv.y, wev, cc1);
            }
        }
        wct[(4 * b + jj) * 64 + a2] = bf16rne(cc0) | (bf16rne(cc1) << 16);
        if (t < 4) {                          // bias column: bc[4b+t] = bp . wevc[t]
            float s = 0.f;
            #pragma unroll 4
            for (int k4 = 0; k4 < 64; ++k4) {
                float4 b4 = *(const float4*)&bp[4 * k4];
                float4 w4 = *(const float4*)&wevc[t][4 * k4];
                s = fmaf(b4.x, w4.x, fmaf(b4.y, w4.y, fmaf(b4.z, w4.z, fmaf(b4.w, w4.w, s))));
            }
            bc[4 * b + t] = s;
        }
    } else {
        // ===== aggregation: 1 node/wave, gathers from L2-resident xb =====
        const int wv = t >> 6, lane = t & 63;
        const int v = (bid - NWB) * 4 + wv;   // < 10000
        int cntv = cursor[v];
        float dv = rsqrtf((float)(cntv + 1));
        int cnt2 = cntv > CAP ? CAP : cntv;
        unsigned self = xb[v * 64 + lane];
        union { unsigned u; float f; } c0u, c1u;
        c0u.u = self << 16; c1u.u = self & 0xFFFF0000u;
        float acc0 = dv * c0u.f, acc1 = dv * c1u.f, wsum = dv;
        const int4* bkt4 = (const int4*)&bucket[v * CAP];
        int j = 0;
        for (; j + 8 <= cnt2; j += 8) {
            int4 sa = bkt4[j >> 2];
            int4 sb = bkt4[(j >> 2) + 1];
            float w0 = rsqrtf((float)(cursor[sa.x] + 1));
            float w1 = rsqrtf((float)(cursor[sa.y] + 1));
            float w2 = rsqrtf((float)(cursor[sa.z] + 1));
            float w3 = rsqrtf((float)(cursor[sa.w] + 1));
            float w4 = rsqrtf((float)(cursor[sb.x] + 1));
            float w5 = rsqrtf((float)(cursor[sb.y] + 1));
            float w6 = rsqrtf((float)(cursor[sb.z] + 1));
            float w7 = rsqrtf((float)(cursor[sb.w] + 1));
            unsigned r0 = xb[sa.x * 64 + lane];
            unsigned r1 = xb[sa.y * 64 + lane];
            unsigned r2 = xb[sa.z * 64 + lane];
            unsigned r3 = xb[sa.w * 64 + lane];
            unsigned r4 = xb[sb.x * 64 + lane];
            unsigned r5 = xb[sb.y * 64 + lane];
            unsigned r6 = xb[sb.z * 64 + lane];
            unsigned r7 = xb[sb.w * 64 + lane];
            union { unsigned u; float f; } a0, a1;
            a0.u = r0 << 16; a1.u = r0 & 0xFFFF0000u;
            acc0 = fmaf(w0, a0.f, acc0); acc1 = fmaf(w0, a1.f, acc1);
            a0.u = r1 << 16; a1.u = r1 & 0xFFFF0000u;
            acc0 = fmaf(w1, a0.f, acc0); acc1 = fmaf(w1, a1.f, acc1);
            a0.u = r2 << 16; a1.u = r2 & 0xFFFF0000u;
            acc0 = fmaf(w2, a0.f, acc0); acc1 = fmaf(w2, a1.f, acc1);
            a0.u = r3 << 16; a1.u = r3 & 0xFFFF0000u;
            acc0 = fmaf(w3, a0.f, acc0); acc1 = fmaf(w3, a1.f, acc1);
            a0.u = r4 << 16; a1.u = r4 & 0xFFFF0000u;
            acc0 = fmaf(w4, a0.f, acc0); acc1 = fmaf(w4, a1.f, acc1);
            a0.u = r5 << 16; a1.u = r5 & 0xFFFF0000u;
            acc0 = fmaf(w5, a0.f, acc0); acc1 = fmaf(w5, a1.f, acc1);
            a0.u = r6 << 16; a1.u = r6 & 0xFFFF0000u;
            acc0 = fmaf(w6, a0.f, acc0); acc1 = fmaf(w6, a1.f, acc1);
            a0.u = r7 << 16; a1.u = r7 & 0xFFFF0000u;
            acc0 = fmaf(w7, a0.f, acc0); acc1 = fmaf(w7, a1.f, acc1);
            wsum += w0 + w1 + w2 + w3 + w4 + w5 + w6 + w7;
        }
        for (; j < cnt2; ++j) {
            int s = bucket[v * CAP + j];
            float ws = rsqrtf((float)(cursor[s] + 1));
            unsigned rr = xb[s * 64 + lane];
            union { unsigned u; float f; } a0, a1;
            a0.u = rr << 16; a1.u = rr & 0xFFFF0000u;
            acc0 = fmaf(ws, a0.f, acc0); acc1 = fmaf(ws, a1.f, acc1);
            wsum += ws;
        }
        yb[v * 64 + lane] = bf16rne(dv * acc0) | (bf16rne(dv * acc1) << 16);
        if (lane == 0) rs[v] = dv * wsum;
    }
}

// ===== K3 (k_out): out = yb @ WcT^T + rs*bc + b_gcn (bf16 MFMA; r0-verified) =====
__global__ __launch_bounds__(256)
void k_out(const unsigned* __restrict__ yb, const unsigned* __restrict__ wct,
           const float* __restrict__ bc, const float* __restrict__ rs,
           const float* __restrict__ b_gcn, float* __restrict__ out) {
    int m0 = blockIdx.x * 16;
    int w = threadIdx.x >> 6, lane = threadIdx.x & 63;
    int q = lane >> 4, ln = lane & 15;
    const int4* yb4  = (const int4*)yb;
    const int4* wct4 = (const int4*)wct;
    union { int4 v; frag_ab f; } a[4];
    #pragma unroll
    for (int kc = 0; kc < 4; ++kc)
        a[kc].v = yb4[(m0 + ln) * 16 + kc * 4 + q];
    float rsv[4];
    #pragma unroll
    for (int r = 0; r < 4; ++r) rsv[r] = rs[m0 + q * 4 + r];
    #pragma unroll
    for (int i = 0; i < 4; ++i) {
        int n0 = (w + 4 * i) * 16;
        union { int4 v; frag_ab f; } b[4];
        #pragma unroll
        for (int kc = 0; kc < 4; ++kc)
            b[kc].v = wct4[(n0 + ln) * 16 + kc * 4 + q];
        frag_cd acc = {0.f, 0.f, 0.f, 0.f};
        #pragma unroll
        for (int kc = 0; kc < 4; ++kc)
            acc = __builtin_amdgcn_mfma_f32_16x16x32_bf16(a[kc].f, b[kc].f, acc, 0, 0, 0);
        int n = n0 + ln;
        float bcv = bc[n], bgv = b_gcn[n];
        #pragma unroll
        for (int r = 0; r < 4; ++r) {
            int m = m0 + q * 4 + r;
            out[m * HID + n] = acc[r] + rsv[r] * bcv + bgv;
        }
    }
}

extern "C" void kernel_launch(void* const* d_in, const int* in_sizes, int n_in,
                              void* d_out, int out_size, void* d_ws, size_t ws_size,
                              hipStream_t stream) {
    const float* x     = (const float*)d_in[0];
    const int*   ei    = (const int*)d_in[1];
    const float* Wp    = (const float*)d_in[2];
    const float* bp    = (const float*)d_in[3];
    const float* W_ih  = (const float*)d_in[4];
    const float* W_hh  = (const float*)d_in[5];
    const float* b_ih  = (const float*)d_in[6];
    const float* b_hh  = (const float*)d_in[7];
    const float* iw    = (const float*)d_in[8];
    const float* b_gcn = (const float*)d_in[9];
    float* out = (float*)d_out;

    char* ws = (char*)d_ws;
    int*      cursor = (int*)     (ws + 0);
    unsigned* wct    = (unsigned*)(ws + 40064);
    float*    bc     = (float*)   (ws + 105600);
    unsigned* xb     = (unsigned*)(ws + 106624);
    unsigned* yb     = (unsigned*)(ws + 2666624);
    float*    rs     = (float*)   (ws + 5226624);
    int*      bucket = (int*)     (ws + 5266624);

    hipMemsetAsync(cursor, 0, N_NODES * sizeof(int), stream);

    k_fx  <<<NBB, 256, 0, stream>>>(x, ei, cursor, xb, bucket);
    k_wagg<<<NWB + 2500, 256, 0, stream>>>(Wp, bp, W_ih, W_hh, b_ih, b_hh, iw,
                                           xb, cursor, bucket, wct, bc, yb, rs);
    k_out <<<625, 256, 0, stream>>>(yb, wct, bc, rs, b_gcn, out);
}